// Round 7
// baseline (370.198 us; speedup 1.0000x reference)
//
#include <hip/hip_runtime.h>
#include <hip/hip_bf16.h>

// Problem dims
constexpr int Bn   = 8;
constexpr int Cin  = 576;
constexpr int Cc   = 192;
constexpr int Hh   = 56;
constexpr int Ww   = 56;
constexpr int HWn  = Hh * Ww;          // 3136
constexpr int CKK  = Cc * 9;           // 1728

// GEMM dims (batch folded into N)
constexpr int GM = 1792;               // 1728 padded
constexpr int GK = 576;
constexpr int GN = Bn * HWn;           // 25088

using f16x8 = __attribute__((ext_vector_type(8))) _Float16;
using f32x4 = __attribute__((ext_vector_type(4))) float;

__device__ __forceinline__ void async_copy16(void* lds, const void* gptr) {
    __builtin_amdgcn_global_load_lds(
        (const __attribute__((address_space(1))) unsigned int*)gptr,
        (__attribute__((address_space(3))) unsigned int*)lds, 16, 0, 0);
}

__device__ __forceinline__ float blo(unsigned int u) { return __uint_as_float(u << 16); }
__device__ __forceinline__ float bhi(unsigned int u) { return __uint_as_float(u & 0xffff0000u); }
__device__ __forceinline__ unsigned short bf16bits(float f) {
    union { __hip_bfloat16 h; unsigned short u; } c; c.h = __float2bfloat16(f); return c.u;
}

// ---------------------------------------------------------------------------
// fc_w (1728x576 f32) -> fcw16 (1792x576 f16, pad rows zero)
// ---------------------------------------------------------------------------
__global__ __launch_bounds__(256) void cast_fcw_kernel(
    const float* __restrict__ fcw, _Float16* __restrict__ out)
{
    int idx = blockIdx.x * 256 + threadIdx.x;
    int e = idx * 4;
    if (e >= GM * GK) return;
    int row = e / GK;
    union { ushort4 u; _Float16 h[4]; } pk;
    if (row < CKK) {
        float4 v = *(const float4*)&fcw[e];
        pk.h[0] = (_Float16)v.x; pk.h[1] = (_Float16)v.y;
        pk.h[2] = (_Float16)v.z; pk.h[3] = (_Float16)v.w;
    } else {
        pk.h[0] = pk.h[1] = pk.h[2] = pk.h[3] = (_Float16)0.f;
    }
    *(ushort4*)&out[e] = pk.u;
}

// ---------------------------------------------------------------------------
// x[b][k][hw] f32 -> xt[b*HW + hw][k] f16
// ---------------------------------------------------------------------------
__global__ __launch_bounds__(256) void transpose_cast_kernel(
    const float* __restrict__ x, _Float16* __restrict__ xt)
{
    __shared__ float t[32][65];
    const int b = blockIdx.z, k0 = blockIdx.y * 32, hw0 = blockIdx.x * 64;
    const int tid = threadIdx.x;
    const int col = tid & 63, kr = tid >> 6;
#pragma unroll
    for (int p = 0; p < 8; p++) {
        int k = kr + p * 4;
        t[k][col] = x[(size_t)(b * Cin + k0 + k) * HWn + hw0 + col];
    }
    __syncthreads();
    const int row = tid >> 2, cq = (tid & 3) * 8;
    union { uint4 u; _Float16 h[8]; } pk;
#pragma unroll
    for (int j = 0; j < 8; j++) pk.h[j] = (_Float16)t[cq + j][row];
    *(uint4*)&xt[(size_t)(b * HWn + hw0 + row) * GK + k0 + cq] = pk.u;
}

// ---------------------------------------------------------------------------
// MFMA GEMM, BK=64: halves the number of barrier drains vs BK=32 (9 K-iters).
// n-fast grid (m-fast regressed: XCD round-robin scatters B-tile sharers
// across non-coherent L2s). XOR swizzle: physical 16B chunk pc of row r holds
// logical chunk pc ^ (r&7) -> fragment b128 reads land 8 lanes/quad uniform.
// Loader LDS dst is lane-contiguous (global_load_lds constraint, m104).
// ---------------------------------------------------------------------------
__global__ __launch_bounds__(256) void gemm_mfma_kernel(
    const _Float16* __restrict__ A, const _Float16* __restrict__ Bm,
    __hip_bfloat16* __restrict__ logits)
{
    __shared__ _Float16 As[128 * 64];
    __shared__ _Float16 Bs[128 * 64];

    const int tid = threadIdx.x;
    const int n0 = blockIdx.x * 128;   // 196 (fast)
    const int m0 = blockIdx.y * 128;   // 14
    const int lane = tid & 63;
    const int wave = tid >> 6;
    const int wm = (wave >> 1) * 64;
    const int wn = (wave & 1) * 64;
    const int lm = lane & 15;
    const int lc = lane >> 4;           // 0..3

    // loader: per q, row = q*32 + (tid>>3), phys chunk tid&7,
    // logical k-chunk = (tid&7) ^ ((tid>>3)&7)  [row&7 == (tid>>3)&7]
    const int lr  = tid >> 3;
    const int koff = (((tid & 7) ^ ((tid >> 3) & 7)) << 3);  // f16 units

    // fragment read offsets (f16 units): row ra, logical chunk lc+4*kk,
    // phys chunk = (lc+4kk) ^ (ra&7); ra&7 == lm&7.
    int offA[2][4], offB[2][4];
#pragma unroll
    for (int kk = 0; kk < 2; kk++)
#pragma unroll
        for (int i = 0; i < 4; i++) {
            int ra = wm + i * 16 + lm;
            offA[kk][i] = ra * 64 + ((((lc + 4 * kk)) ^ (lm & 7)) << 3);
            int rb = wn + i * 16 + lm;
            offB[kk][i] = rb * 64 + ((((lc + 4 * kk)) ^ (lm & 7)) << 3);
        }

    f32x4 acc[4][4] = {};

    for (int k0 = 0; k0 < GK; k0 += 64) {
#pragma unroll
        for (int q = 0; q < 4; q++) {
            int row = q * 32 + lr;
            async_copy16(&As[q * 2048 + (size_t)tid * 8],
                         &A[(size_t)(m0 + row) * GK + k0 + koff]);
            async_copy16(&Bs[q * 2048 + (size_t)tid * 8],
                         &Bm[(size_t)(n0 + row) * GK + k0 + koff]);
        }
        __syncthreads();
#pragma unroll
        for (int kk = 0; kk < 2; kk++) {
            f16x8 af[4], bf[4];
#pragma unroll
            for (int i = 0; i < 4; i++) {
                af[i] = *(const f16x8*)&As[offA[kk][i]];
                bf[i] = *(const f16x8*)&Bs[offB[kk][i]];
            }
#pragma unroll
            for (int i = 0; i < 4; i++)
#pragma unroll
                for (int j = 0; j < 4; j++)
                    acc[i][j] = __builtin_amdgcn_mfma_f32_16x16x32_f16(bf[j], af[i], acc[i][j], 0, 0, 0);
        }
        __syncthreads();
    }

    // Epilogue: lane holds 4 consecutive n (hw) for m = m0+wm+i*16+lm.
    const int mcol = m0 + wm + lm;
#pragma unroll
    for (int i = 0; i < 4; i++) {
        int m = mcol + i * 16;
        if (m >= CKK) continue;
#pragma unroll
        for (int j = 0; j < 4; j++) {
            int n = n0 + wn + j * 16 + lc * 4;   // 4 consecutive n, same batch
            int b = n / HWn, hw = n - b * HWn;
            uint2 pk;
            pk.x = (unsigned)bf16bits(acc[i][j][0]) | ((unsigned)bf16bits(acc[i][j][1]) << 16);
            pk.y = (unsigned)bf16bits(acc[i][j][2]) | ((unsigned)bf16bits(acc[i][j][3]) << 16);
            *(uint2*)&logits[((size_t)b * CKK + m) * HWn + hw] = pk;
        }
    }
}

// ---------------------------------------------------------------------------
// FUSED conv1 + softmax + conv2 + aggregation.
// xt stride 61 (odd dword stride -> win b32 reads ~2-way instead of 8-way).
// phase2 i-loop fully unrolled (lg[9][8] must stay in VGPRs — R4 lesson).
// ---------------------------------------------------------------------------
__global__ __launch_bounds__(256) void conv_fused_kernel(
    const float* __restrict__ x, const float* __restrict__ w1,
    const __hip_bfloat16* __restrict__ logits,
    const float* __restrict__ w2, float* __restrict__ out)
{
    const int c = blockIdx.x, hb = blockIdx.y, b = blockIdx.z;
    const int tid = threadIdx.x;
    const int h0 = hb * 28;

    __shared__ float xt[3][32][61];          // x rows h0-2..h0+29, col = w+1
    __shared__ unsigned short ft[9][30][72]; // feat rows h0-1..h0+28, col = fw+2

    // ---- stage x tile (rows h0-2 .. h0+29, zero-padded) ----
    for (int idx = tid; idx < 1344; idx += 256) {      // 3*32*14 float4 groups
        int d = idx / 448, rem = idx - d * 448;
        int r = rem / 14, g = rem - r * 14;
        int h = h0 - 2 + r;
        float4 v = {0.f, 0.f, 0.f, 0.f};
        if (h >= 0 && h < Hh)
            v = *(const float4*)&x[((size_t)(b * Cin + 3 * c + d) * Hh + h) * Ww + 4 * g];
        xt[d][r][1 + 4 * g + 0] = v.x;
        xt[d][r][1 + 4 * g + 1] = v.y;
        xt[d][r][1 + 4 * g + 2] = v.z;
        xt[d][r][1 + 4 * g + 3] = v.w;
    }
    for (int idx = tid; idx < 192; idx += 256) {       // cols 0 (w=-1), 57 (w=56)
        int d = idx / 64, rem = idx - d * 64;
        int r = rem >> 1, col = (rem & 1) ? 57 : 0;
        xt[d][r][col] = 0.f;
    }
    __syncthreads();

    // ---- phase 1: conv1 -> ft (30 feat rows x 7 segs = 210 strips) ----
    if (tid < 210) {
        const int row = tid / 7, seg = tid - (tid / 7) * 7;
        const int w0 = seg * 8;
        const int fh = h0 - 1 + row;                   // feat row
        const bool valid = (fh >= 0) && (fh < Hh);

        float win[3][3][10];
#pragma unroll
        for (int d = 0; d < 3; d++)
#pragma unroll
            for (int u = 0; u < 3; u++)
#pragma unroll
                for (int k = 0; k < 10; k++)
                    win[d][u][k] = xt[d][row + u][w0 + k];

#pragma unroll 1
        for (int i = 0; i < 9; i++) {
            const float* wp = w1 + ((size_t)i * Cc + c) * 27;
            float wgt[27];
#pragma unroll
            for (int j = 0; j < 27; j++) wgt[j] = wp[j];
            float acc[8] = {};
#pragma unroll
            for (int d = 0; d < 3; d++)
#pragma unroll
                for (int u = 0; u < 3; u++)
#pragma unroll
                    for (int v = 0; v < 3; v++) {
                        float wv = wgt[d * 9 + u * 3 + v];
#pragma unroll
                        for (int p = 0; p < 8; p++)
                            acc[p] += win[d][u][p + v] * wv;
                    }
            unsigned int pk[4];
            if (valid) {
#pragma unroll
                for (int q = 0; q < 4; q++)
                    pk[q] = (unsigned)bf16bits(fmaxf(acc[2 * q], 0.f)) |
                            ((unsigned)bf16bits(fmaxf(acc[2 * q + 1], 0.f)) << 16);
            } else {
                pk[0] = pk[1] = pk[2] = pk[3] = 0u;
            }
            unsigned int* dst = (unsigned int*)&ft[i][row][2 + w0];
            dst[0] = pk[0]; dst[1] = pk[1]; dst[2] = pk[2]; dst[3] = pk[3];
        }
    }
    // ft edge zeros: cols 0,1 (fw=-2,-1), 58,59 (fw=56,57); disjoint from above
    for (int idx = tid; idx < 1080; idx += 256) {
        int i = idx / 120, rem = idx - i * 120;
        int r = rem >> 2, e = rem & 3;
        int col = (e < 2) ? e : 56 + e;
        ft[i][r][col] = 0;
    }
    __syncthreads();

    // ---- phase 2: softmax + conv2 + aggregation (28 rows x 7 segs) ----
    if (tid < 196) {
        const int row = tid / 7, seg = tid - (tid / 7) * 7;
        const int w0 = 8 * seg;
        const int hw = (h0 + row) * Ww + w0;

        float lg[9][8];
        const __hip_bfloat16* lbase = logits + ((size_t)b * CKK + c * 9) * HWn + hw;
#pragma unroll
        for (int i = 0; i < 9; i++) {
            uint4 lv = *(const uint4*)&lbase[(size_t)i * HWn];
            lg[i][0] = blo(lv.x); lg[i][1] = bhi(lv.x);
            lg[i][2] = blo(lv.y); lg[i][3] = bhi(lv.y);
            lg[i][4] = blo(lv.z); lg[i][5] = bhi(lv.z);
            lg[i][6] = blo(lv.w); lg[i][7] = bhi(lv.w);
        }
#pragma unroll
        for (int p = 0; p < 8; p++) {
            float mx = lg[0][p];
#pragma unroll
            for (int i = 1; i < 9; i++) mx = fmaxf(mx, lg[i][p]);
            float sum = 0.f;
#pragma unroll
            for (int i = 0; i < 9; i++) { lg[i][p] = __expf(lg[i][p] - mx); sum += lg[i][p]; }
            float inv = __builtin_amdgcn_rcpf(sum);
#pragma unroll
            for (int i = 0; i < 9; i++) lg[i][p] *= inv;
        }

        float oacc[8] = {};
#pragma unroll
        for (int i = 0; i < 9; i++) {
            const float* wp = w2 + ((size_t)i * Cc + c) * 9;
            float wgt[9];
#pragma unroll
            for (int j = 0; j < 9; j++) wgt[j] = wp[j];
            float cacc[8] = {};
#pragma unroll
            for (int u = 0; u < 3; u++) {
                const unsigned short* fr = &ft[i][row + u][w0];
                uint4 a = *(const uint4*)fr;
                uint2 bq = *(const uint2*)(fr + 8);
                float wf[11];
                wf[1] = bhi(a.x);
                wf[2] = blo(a.y);  wf[3] = bhi(a.y);
                wf[4] = blo(a.z);  wf[5] = bhi(a.z);
                wf[6] = blo(a.w);  wf[7] = bhi(a.w);
                wf[8] = blo(bq.x); wf[9] = bhi(bq.x);
                wf[10] = blo(bq.y);
#pragma unroll
                for (int v = 0; v < 3; v++) {
                    float wv = wgt[u * 3 + v];
#pragma unroll
                    for (int p = 0; p < 8; p++)
                        cacc[p] += wf[p + v + 1] * wv;
                }
            }
#pragma unroll
            for (int p = 0; p < 8; p++) oacc[p] += cacc[p] * lg[i][p];
        }

        float* obase = out + ((size_t)(b * Cc + c)) * HWn + hw;
        float4 o0, o1;
        o0.x = oacc[0]; o0.y = oacc[1]; o0.z = oacc[2]; o0.w = oacc[3];
        o1.x = oacc[4]; o1.y = oacc[5]; o1.z = oacc[6]; o1.w = oacc[7];
        *(float4*)&obase[0] = o0;
        *(float4*)&obase[4] = o1;
    }
}

// ---------------------------------------------------------------------------
extern "C" void kernel_launch(void* const* d_in, const int* in_sizes, int n_in,
                              void* d_out, int out_size, void* d_ws, size_t ws_size,
                              hipStream_t stream)
{
    const float* x    = (const float*)d_in[0];
    const float* fc_w = (const float*)d_in[1];
    const float* w1   = (const float*)d_in[2];
    const float* w2   = (const float*)d_in[3];
    float* out = (float*)d_out;

    // ws layout: [logits bf16 86.7MB][xt f16 28.9MB][fcw16 f16 2.1MB]
    char* ws = (char*)d_ws;
    __hip_bfloat16* logits = (__hip_bfloat16*)ws;
    _Float16* xt    = (_Float16*)(ws + (size_t)Bn * CKK * HWn * 2);
    _Float16* fcw16 = (_Float16*)(ws + (size_t)Bn * CKK * HWn * 2 + (size_t)GN * GK * 2);

    cast_fcw_kernel<<<(GM * GK / 4 + 255) / 256, 256, 0, stream>>>(fc_w, fcw16);
    transpose_cast_kernel<<<dim3(HWn / 64, GK / 32, Bn), 256, 0, stream>>>(x, xt);
    gemm_mfma_kernel<<<dim3(GN / 128, GM / 128), 256, 0, stream>>>(fcw16, xt, logits);
    conv_fused_kernel<<<dim3(Cc, 2, Bn), 256, 0, stream>>>(x, w1, logits, w2, out);
}

// Round 8
// 275.665 us; speedup vs baseline: 1.3429x; 1.3429x over previous
//
#include <hip/hip_runtime.h>
#include <hip/hip_bf16.h>

// Problem dims
constexpr int Bn   = 8;
constexpr int Cin  = 576;
constexpr int Cc   = 192;
constexpr int Hh   = 56;
constexpr int Ww   = 56;
constexpr int HWn  = Hh * Ww;          // 3136
constexpr int CKK  = Cc * 9;           // 1728

// GEMM dims (batch folded into N)
constexpr int GM = 1792;               // 1728 padded
constexpr int GK = 576;
constexpr int GN = Bn * HWn;           // 25088

using f16x8 = __attribute__((ext_vector_type(8))) _Float16;
using f32x4 = __attribute__((ext_vector_type(4))) float;

__device__ __forceinline__ void async_copy16(void* lds, const void* gptr) {
    __builtin_amdgcn_global_load_lds(
        (const __attribute__((address_space(1))) unsigned int*)gptr,
        (__attribute__((address_space(3))) unsigned int*)lds, 16, 0, 0);
}

__device__ __forceinline__ float blo(unsigned int u) { return __uint_as_float(u << 16); }
__device__ __forceinline__ float bhi(unsigned int u) { return __uint_as_float(u & 0xffff0000u); }
__device__ __forceinline__ unsigned short bf16bits(float f) {
    union { __hip_bfloat16 h; unsigned short u; } c; c.h = __float2bfloat16(f); return c.u;
}

// ---------------------------------------------------------------------------
// fc_w (1728x576 f32) -> fcw16 (1792x576 f16, pad rows zero)
// ---------------------------------------------------------------------------
__global__ __launch_bounds__(256) void cast_fcw_kernel(
    const float* __restrict__ fcw, _Float16* __restrict__ out)
{
    int idx = blockIdx.x * 256 + threadIdx.x;
    int e = idx * 4;
    if (e >= GM * GK) return;
    int row = e / GK;
    union { ushort4 u; _Float16 h[4]; } pk;
    if (row < CKK) {
        float4 v = *(const float4*)&fcw[e];
        pk.h[0] = (_Float16)v.x; pk.h[1] = (_Float16)v.y;
        pk.h[2] = (_Float16)v.z; pk.h[3] = (_Float16)v.w;
    } else {
        pk.h[0] = pk.h[1] = pk.h[2] = pk.h[3] = (_Float16)0.f;
    }
    *(ushort4*)&out[e] = pk.u;
}

// ---------------------------------------------------------------------------
// x[b][k][hw] f32 -> xt[b*HW + hw][k] f16
// ---------------------------------------------------------------------------
__global__ __launch_bounds__(256) void transpose_cast_kernel(
    const float* __restrict__ x, _Float16* __restrict__ xt)
{
    __shared__ float t[32][65];
    const int b = blockIdx.z, k0 = blockIdx.y * 32, hw0 = blockIdx.x * 64;
    const int tid = threadIdx.x;
    const int col = tid & 63, kr = tid >> 6;
#pragma unroll
    for (int p = 0; p < 8; p++) {
        int k = kr + p * 4;
        t[k][col] = x[(size_t)(b * Cin + k0 + k) * HWn + hw0 + col];
    }
    __syncthreads();
    const int row = tid >> 2, cq = (tid & 3) * 8;
    union { uint4 u; _Float16 h[8]; } pk;
#pragma unroll
    for (int j = 0; j < 8; j++) pk.h[j] = (_Float16)t[cq + j][row];
    *(uint4*)&xt[(size_t)(b * HWn + hw0 + row) * GK + k0 + cq] = pk.u;
}

// ---------------------------------------------------------------------------
// MFMA GEMM — exact R5 body (BK=32, measured 94 us, conflicts=0) with an
// XCD-aware 1-D remap: xcd g = lin&7 processes all 14 m-tiles per n-tile
// (A 2MB L2-resident per XCD; B-tile footprint bounded under either
// round-robin or chunked XCD assignment).
// ---------------------------------------------------------------------------
__global__ __launch_bounds__(256) void gemm_mfma_kernel(
    const _Float16* __restrict__ A, const _Float16* __restrict__ Bm,
    __hip_bfloat16* __restrict__ logits)
{
    const int lin = blockIdx.x;
    const int g = lin & 7, s = lin >> 3;        // s: 0..349
    const int mt = s % 14, nt = (s / 14) * 8 + g;
    if (nt >= 196) return;

    __shared__ _Float16 As[128 * 32];
    __shared__ _Float16 Bs[128 * 32];

    const int tid = threadIdx.x;
    const int n0 = nt * 128;
    const int m0 = mt * 128;
    const int lane = tid & 63;
    const int wave = tid >> 6;
    const int wm = (wave >> 1) * 64;
    const int wn = (wave & 1) * 64;
    const int lm = lane & 15;
    const int lc = lane >> 4;           // logical k-chunk (8 f16 = 16B)

    const int lrow = tid >> 2;
    const int koff = (((tid & 3) ^ ((tid >> 3) & 3)) << 3);  // f16 units

    int offA[4], offB[4];
#pragma unroll
    for (int i = 0; i < 4; i++) {
        int ra = wm + i * 16 + lm;
        offA[i] = ra * 32 + ((lc ^ ((ra >> 1) & 3)) << 3);
        int rb = wn + i * 16 + lm;
        offB[i] = rb * 32 + ((lc ^ ((rb >> 1) & 3)) << 3);
    }

    f32x4 acc[4][4] = {};

    for (int k0 = 0; k0 < GK; k0 += 32) {
        async_copy16(&As[(size_t)tid * 8],        &A[(size_t)(m0 + lrow) * GK + k0 + koff]);
        async_copy16(&As[2048 + (size_t)tid * 8], &A[(size_t)(m0 + 64 + lrow) * GK + k0 + koff]);
        async_copy16(&Bs[(size_t)tid * 8],        &Bm[(size_t)(n0 + lrow) * GK + k0 + koff]);
        async_copy16(&Bs[2048 + (size_t)tid * 8], &Bm[(size_t)(n0 + 64 + lrow) * GK + k0 + koff]);
        __syncthreads();
        f16x8 af[4], bf[4];
#pragma unroll
        for (int i = 0; i < 4; i++) {
            af[i] = *(const f16x8*)&As[offA[i]];
            bf[i] = *(const f16x8*)&Bs[offB[i]];
        }
#pragma unroll
        for (int i = 0; i < 4; i++)
#pragma unroll
            for (int j = 0; j < 4; j++)
                acc[i][j] = __builtin_amdgcn_mfma_f32_16x16x32_f16(bf[j], af[i], acc[i][j], 0, 0, 0);
        __syncthreads();
    }

    const int mcol = m0 + wm + lm;
#pragma unroll
    for (int i = 0; i < 4; i++) {
        int m = mcol + i * 16;
        if (m >= CKK) continue;
#pragma unroll
        for (int j = 0; j < 4; j++) {
            int n = n0 + wn + j * 16 + lc * 4;   // 4 consecutive n, same batch
            int b = n / HWn, hw = n - b * HWn;
            uint2 pk;
            pk.x = (unsigned)bf16bits(acc[i][j][0]) | ((unsigned)bf16bits(acc[i][j][1]) << 16);
            pk.y = (unsigned)bf16bits(acc[i][j][2]) | ((unsigned)bf16bits(acc[i][j][3]) << 16);
            *(uint2*)&logits[((size_t)b * CKK + m) * HWn + hw] = pk;
        }
    }
}

// ---------------------------------------------------------------------------
// FUSED conv1 + softmax + conv2 + aggregation — occupancy-focused rework.
// 14-row tiles, 4-px strips: LDS 33.9 KB + VGPR<=128 -> 4 blocks/CU (16
// waves, was 8). Logits prefetched before phase 1 (latency hidden).
// Phase-2 i-loop fully unrolled (lg must stay in VGPRs — R4 lesson).
// ---------------------------------------------------------------------------
__global__ __launch_bounds__(256, 4) void conv_fused_kernel(
    const float* __restrict__ x, const float* __restrict__ w1,
    const __hip_bfloat16* __restrict__ logits,
    const float* __restrict__ w2, float* __restrict__ out)
{
    const int c = blockIdx.x, hb = blockIdx.y, b = blockIdx.z;
    const int tid = threadIdx.x;
    const int h0 = hb * 14;

    __shared__ float xt[3][18][61];           // x rows h0-2..h0+15, col = w+1
    __shared__ unsigned short ft[9][16][72];  // feat rows h0-1..h0+14, col = fw+2

    // ---- stage x tile (rows h0-2..h0+15, zero-padded) ----
    for (int idx = tid; idx < 756; idx += 256) {       // 3*18*14 float4 groups
        int d = idx / 252, rem = idx - d * 252;
        int r = rem / 14, g = rem - r * 14;
        int h = h0 - 2 + r;
        float4 v = {0.f, 0.f, 0.f, 0.f};
        if (h >= 0 && h < Hh)
            v = *(const float4*)&x[((size_t)(b * Cin + 3 * c + d) * Hh + h) * Ww + 4 * g];
        xt[d][r][1 + 4 * g + 0] = v.x;
        xt[d][r][1 + 4 * g + 1] = v.y;
        xt[d][r][1 + 4 * g + 2] = v.z;
        xt[d][r][1 + 4 * g + 3] = v.w;
    }
    for (int idx = tid; idx < 108; idx += 256) {       // x edge cols 0, 57
        int d = idx / 36, rem = idx - d * 36;
        int r = rem >> 1, col = (rem & 1) ? 57 : 0;
        xt[d][r][col] = 0.f;
    }
    // ft edge zeros: cols (0,1) and (58,59), one b32 each; disjoint from
    // phase-1 writes (cols 2..57+2). 9*16*2 = 288 writes.
    for (int idx = tid; idx < 288; idx += 256) {
        int i = idx / 32, rem = idx - i * 32;
        int r = rem >> 1, side = rem & 1;
        *(unsigned int*)&ft[i][r][side ? 58 : 0] = 0u;
    }

    // ---- prefetch logits (no LDS dependency; latency hides behind staging)
    const bool p2 = tid < 196;
    const int row2 = tid / 14, seg2 = tid - row2 * 14;
    const int hw2 = (h0 + row2) * Ww + 4 * seg2;
    uint2 lv[9];
    if (p2) {
        const __hip_bfloat16* lbase = logits + ((size_t)b * CKK + c * 9) * HWn + hw2;
#pragma unroll
        for (int i = 0; i < 9; i++) lv[i] = *(const uint2*)&lbase[(size_t)i * HWn];
    }
    __syncthreads();

    // ---- phase 1: conv1 -> ft (16 feat rows x 14 segs of 4 px = 224) ----
    if (tid < 224) {
        const int row = tid / 14, seg = tid - (tid / 14) * 14;
        const int w0 = 4 * seg;
        const int fh = h0 - 1 + row;
        const bool valid = (fh >= 0) && (fh < Hh);

        float win[3][3][6];
#pragma unroll
        for (int d = 0; d < 3; d++)
#pragma unroll
            for (int u = 0; u < 3; u++)
#pragma unroll
                for (int k = 0; k < 6; k++)
                    win[d][u][k] = xt[d][row + u][w0 + k];

#pragma unroll 1
        for (int i = 0; i < 9; i++) {
            const float* wp = w1 + ((size_t)i * Cc + c) * 27;
            float wgt[27];
#pragma unroll
            for (int j = 0; j < 27; j++) wgt[j] = wp[j];
            float acc[4] = {};
#pragma unroll
            for (int d = 0; d < 3; d++)
#pragma unroll
                for (int u = 0; u < 3; u++)
#pragma unroll
                    for (int v = 0; v < 3; v++) {
                        float wv = wgt[d * 9 + u * 3 + v];
#pragma unroll
                        for (int p = 0; p < 4; p++)
                            acc[p] += win[d][u][p + v] * wv;
                    }
            unsigned pk0 = 0u, pk1 = 0u;
            if (valid) {
                pk0 = (unsigned)bf16bits(fmaxf(acc[0], 0.f)) |
                      ((unsigned)bf16bits(fmaxf(acc[1], 0.f)) << 16);
                pk1 = (unsigned)bf16bits(fmaxf(acc[2], 0.f)) |
                      ((unsigned)bf16bits(fmaxf(acc[3], 0.f)) << 16);
            }
            unsigned int* dst = (unsigned int*)&ft[i][row][2 + w0];
            dst[0] = pk0; dst[1] = pk1;
        }
    }
    __syncthreads();

    // ---- phase 2: softmax + conv2 + aggregation (14 rows x 14 segs) ----
    if (p2) {
        const int w0 = 4 * seg2;

        float lg[9][4];
#pragma unroll
        for (int i = 0; i < 9; i++) {
            lg[i][0] = blo(lv[i].x); lg[i][1] = bhi(lv[i].x);
            lg[i][2] = blo(lv[i].y); lg[i][3] = bhi(lv[i].y);
        }
#pragma unroll
        for (int p = 0; p < 4; p++) {
            float mx = lg[0][p];
#pragma unroll
            for (int i = 1; i < 9; i++) mx = fmaxf(mx, lg[i][p]);
            float sum = 0.f;
#pragma unroll
            for (int i = 0; i < 9; i++) { lg[i][p] = __expf(lg[i][p] - mx); sum += lg[i][p]; }
            float inv = __builtin_amdgcn_rcpf(sum);
#pragma unroll
            for (int i = 0; i < 9; i++) lg[i][p] *= inv;
        }

        float oacc[4] = {};
#pragma unroll
        for (int i = 0; i < 9; i++) {
            const float* wp = w2 + ((size_t)i * Cc + c) * 9;
            float wgt[9];
#pragma unroll
            for (int j = 0; j < 9; j++) wgt[j] = wp[j];
            float cacc[4] = {};
#pragma unroll
            for (int u = 0; u < 3; u++) {
                const unsigned short* fr = &ft[i][row2 + u][w0];  // col w0 = fw w0-2
                uint2 a = *(const uint2*)fr;        // cols w0..w0+3
                uint2 b2 = *(const uint2*)(fr + 4); // cols w0+4..w0+7
                float wf[8];
                wf[0] = blo(a.x);  wf[1] = bhi(a.x);
                wf[2] = blo(a.y);  wf[3] = bhi(a.y);
                wf[4] = blo(b2.x); wf[5] = bhi(b2.x);
                wf[6] = blo(b2.y); wf[7] = bhi(b2.y);
#pragma unroll
                for (int v = 0; v < 3; v++) {
                    float wv = wgt[u * 3 + v];
#pragma unroll
                    for (int p = 0; p < 4; p++)
                        cacc[p] += wf[p + v + 1] * wv;
                }
            }
#pragma unroll
            for (int p = 0; p < 4; p++) oacc[p] += cacc[p] * lg[i][p];
        }

        float4 o;
        o.x = oacc[0]; o.y = oacc[1]; o.z = oacc[2]; o.w = oacc[3];
        *(float4*)&out[((size_t)(b * Cc + c)) * HWn + hw2] = o;
    }
}

// ---------------------------------------------------------------------------
extern "C" void kernel_launch(void* const* d_in, const int* in_sizes, int n_in,
                              void* d_out, int out_size, void* d_ws, size_t ws_size,
                              hipStream_t stream)
{
    const float* x    = (const float*)d_in[0];
    const float* fc_w = (const float*)d_in[1];
    const float* w1   = (const float*)d_in[2];
    const float* w2   = (const float*)d_in[3];
    float* out = (float*)d_out;

    // ws layout: [logits bf16 86.7MB][xt f16 28.9MB][fcw16 f16 2.1MB]
    char* ws = (char*)d_ws;
    __hip_bfloat16* logits = (__hip_bfloat16*)ws;
    _Float16* xt    = (_Float16*)(ws + (size_t)Bn * CKK * HWn * 2);
    _Float16* fcw16 = (_Float16*)(ws + (size_t)Bn * CKK * HWn * 2 + (size_t)GN * GK * 2);

    cast_fcw_kernel<<<(GM * GK / 4 + 255) / 256, 256, 0, stream>>>(fc_w, fcw16);
    transpose_cast_kernel<<<dim3(HWn / 64, GK / 32, Bn), 256, 0, stream>>>(x, xt);
    gemm_mfma_kernel<<<8 * 25 * 14, 256, 0, stream>>>(fcw16, xt, logits);
    conv_fused_kernel<<<dim3(Cc, 4, Bn), 256, 0, stream>>>(x, w1, logits, w2, out);
}